// Round 1
// baseline (1861.563 us; speedup 1.0000x reference)
//
#include <hip/hip_runtime.h>
#include <math.h>

#define B_ 32
#define T_ 128
#define H_ 768
#define N_ 1024
#define M_ 131072
#define DK 128
#define DV 512
#define NROWS 512
#define VPR 256
#define KTOP 32

// ---- workspace layout (bytes) ----
#define WS_QF64   ((size_t)0)
#define WS_QF32   (WS_QF64 + (size_t)N_*DK*8)
#define WS_RMAX1  (WS_QF32 + (size_t)N_*DK*4)
#define WS_RMAX2  (WS_RMAX1 + (size_t)N_*NROWS*4)
#define WS_RARG1  (WS_RMAX2 + (size_t)N_*NROWS*4)
#define WS_RARG2  (WS_RARG1 + (size_t)N_*NROWS*4)
#define WS_POOLED (WS_RARG2 + (size_t)N_*NROWS*4)
#define WS_DELTA  (WS_POOLED + (size_t)N_*DV*4)
// total ~24.6 MB

// ---------------------------------------------------------------------------
// Kernel 1: queries = concat(start_enc, end_enc) @ query_w + query_b, f64 acc
// ---------------------------------------------------------------------------
__global__ __launch_bounds__(128) void k_queries(
    const float* __restrict__ enc, const int* __restrict__ mbp,
    const int* __restrict__ msp, const int* __restrict__ mep,
    const float* __restrict__ qw, const float* __restrict__ qb,
    double* __restrict__ qf64, float* __restrict__ qf32) {
  int m = blockIdx.x, d = threadIdx.x;
  __shared__ float se[H_], ee[H_];
  int b = mbp[m], s = msp[m], e = mep[m];
  const float* rs = enc + ((size_t)(b * T_ + s)) * H_;
  const float* re = enc + ((size_t)(b * T_ + e)) * H_;
  for (int h = d; h < H_; h += 128) { se[h] = rs[h]; ee[h] = re[h]; }
  __syncthreads();
  double acc = (double)qb[d];
  for (int h = 0; h < H_; ++h) acc += (double)se[h] * (double)qw[(size_t)h * DK + d];
  for (int h = 0; h < H_; ++h) acc += (double)ee[h] * (double)qw[(size_t)(H_ + h) * DK + d];
  qf64[(size_t)m * DK + d] = acc;
  qf32[(size_t)m * DK + d] = (float)acc;
}

// ---------------------------------------------------------------------------
// top-2 insert with jax tie rule (value desc, index asc). Indices are unique,
// so duplicate-reinsertion cannot occur in our merges.
// ---------------------------------------------------------------------------
__device__ __forceinline__ void top2_ins(float v, int i, float& v1, int& i1,
                                         float& v2, int& i2) {
  if (v > v1 || (v == v1 && i < i1)) { v2 = v1; i2 = i1; v1 = v; i1 = i; }
  else if (v > v2 || (v == v2 && i < i2)) { v2 = v; i2 = i; }
}

// ---------------------------------------------------------------------------
// Kernel 2: fp32 scoring GEMM fused with per-row top-2 reduction.
// Block: 256 threads = 16 mg x 16 kg; per-thread 4 mentions x 4 keys.
// Block tile: 64 mentions x 1 row (256 keys, processed as 4 groups of 64,
// each group split into 2 dim-chunks of 64).
// ---------------------------------------------------------------------------
#define TM 64
__global__ __launch_bounds__(256) void k_score(
    const float* __restrict__ qf32, const float* __restrict__ keys,
    float* __restrict__ rmax1, float* __restrict__ rmax2,
    int* __restrict__ rarg1, int* __restrict__ rarg2) {
  __shared__ __align__(16) float q_s[TM * 132];   // stride 132: conflict-free reads
  __shared__ __align__(16) float k_s[64 * 68];    // stride 68
  int row = blockIdx.x;   // 0..511
  int mt  = blockIdx.y;   // 0..15
  int tid = threadIdx.x;
  int mg = tid >> 4, kg = tid & 15;

  // stage q tile (64 x 128), coalesced
  for (int i = tid; i < TM * 32; i += 256) {
    int r = i >> 5, c4 = (i & 31) << 2;
    *(float4*)(q_s + r * 132 + c4) =
        *(const float4*)(qf32 + ((size_t)(mt * TM + r)) * DK + c4);
  }

  float V1[4], V2[4]; int I1[4], I2[4];
#pragma unroll
  for (int mm = 0; mm < 4; ++mm) {
    V1[mm] = -INFINITY; V2[mm] = -INFINITY; I1[mm] = 0x7fffffff; I2[mm] = 0x7fffffff;
  }

  for (int g = 0; g < 4; ++g) {          // 4 key-groups of 64 within the row
    float acc[4][4] = {};
    for (int dc = 0; dc < 2; ++dc) {     // 2 dim-chunks of 64
      __syncthreads();
      for (int i = tid; i < 64 * 16; i += 256) {
        int r = i >> 4, c4 = (i & 15) << 2;
        *(float4*)(k_s + r * 68 + c4) =
            *(const float4*)(keys + ((size_t)row * VPR + g * 64 + r) * DK + dc * 64 + c4);
      }
      __syncthreads();
#pragma unroll 4
      for (int d = 0; d < 64; d += 4) {
        float4 qv[4], kv[4];
#pragma unroll
        for (int mm = 0; mm < 4; ++mm)
          qv[mm] = *(const float4*)(q_s + (mm * 16 + mg) * 132 + dc * 64 + d);
#pragma unroll
        for (int kk = 0; kk < 4; ++kk)
          kv[kk] = *(const float4*)(k_s + (kk * 16 + kg) * 68 + d);
#pragma unroll
        for (int mm = 0; mm < 4; ++mm)
#pragma unroll
          for (int kk = 0; kk < 4; ++kk)
            acc[mm][kk] += qv[mm].x * kv[kk].x + qv[mm].y * kv[kk].y +
                           qv[mm].z * kv[kk].z + qv[mm].w * kv[kk].w;
      }
    }
    // reduce this key-group: per-thread top-2, then butterfly over 16 kg lanes
#pragma unroll
    for (int mm = 0; mm < 4; ++mm) {
      float v1 = -INFINITY, v2 = -INFINITY; int i1 = 0x7fffffff, i2 = 0x7fffffff;
#pragma unroll
      for (int kk = 0; kk < 4; ++kk)
        top2_ins(acc[mm][kk], g * 64 + kk * 16 + kg, v1, i1, v2, i2);
#pragma unroll
      for (int off = 8; off >= 1; off >>= 1) {
        float w1 = __shfl_xor(v1, off, 16);
        int   j1 = __shfl_xor(i1, off, 16);
        float w2 = __shfl_xor(v2, off, 16);
        int   j2 = __shfl_xor(i2, off, 16);
        top2_ins(w1, j1, v1, i1, v2, i2);
        top2_ins(w2, j2, v1, i1, v2, i2);
      }
      top2_ins(v1, i1, V1[mm], I1[mm], V2[mm], I2[mm]);
      top2_ins(v2, i2, V1[mm], I1[mm], V2[mm], I2[mm]);
    }
  }
  if (kg == 0) {
#pragma unroll
    for (int mm = 0; mm < 4; ++mm) {
      size_t o = ((size_t)(mt * TM + mm * 16 + mg)) * NROWS + row;
      rmax1[o] = V1[mm]; rmax2[o] = V2[mm]; rarg1[o] = I1[mm]; rarg2[o] = I2[mm];
    }
  }
}

// ---------------------------------------------------------------------------
// Kernel 3: per-mention exact selection (f64 rescoring), softmax, pooling.
// ---------------------------------------------------------------------------
__global__ __launch_bounds__(256) void k_select(
    const double* __restrict__ qf64, const float* __restrict__ keys,
    const float* __restrict__ rmax1, const float* __restrict__ rmax2,
    const int* __restrict__ rarg1, const int* __restrict__ rarg2,
    const int* __restrict__ memmask, const int* __restrict__ eids,
    const float* __restrict__ mvals,
    float* __restrict__ out_w, float* __restrict__ out_ids,
    float* __restrict__ pooled) {
  int m = blockIdx.x, tid = threadIdx.x;
  __shared__ double q_d[DK];
  __shared__ float  vals[NROWS];
  __shared__ int    slotRow[64];
  __shared__ float  slotV[64];
  __shared__ double cval[64];
  __shared__ int    carg[64];
  __shared__ float  Tsh;
  __shared__ int    Csh;
  __shared__ int    fgid[KTOP];
  __shared__ double fval[KTOP];
  __shared__ float  wsm[KTOP];

  for (int i = tid; i < DK; i += 256) q_d[i] = qf64[(size_t)m * DK + i];
  for (int i = tid; i < NROWS; i += 256) vals[i] = rmax1[(size_t)m * NROWS + i];
  __syncthreads();

  // exact rank of each row by (approx max desc, row asc); keep top 64 slots
  for (int i = tid; i < NROWS; i += 256) {
    float v = vals[i]; int rank = 0;
    for (int j = 0; j < NROWS; ++j) {
      float u = vals[j];
      rank += (u > v) | ((u == v) & (j < i));
    }
    if (rank < 64) { slotRow[rank] = i; slotV[rank] = v; }
    if (rank == KTOP - 1) Tsh = v - 0.01f;   // 2*eps safety margin
  }
  __syncthreads();
  if (tid == 0) {
    int C = KTOP;
    while (C < 64 && slotV[C] >= Tsh) ++C;
    Csh = C;
  }
  __syncthreads();
  int C = Csh;

  // f64 rescore candidate rows (top-1, and top-2 if within margin)
  if (tid < C) {
    int row = slotRow[tid];
    size_t o = (size_t)m * NROWS + row;
    float v1 = vals[row], v2 = rmax2[o];
    int i1 = rarg1[o], i2 = rarg2[o];
    const float* kp = keys + ((size_t)row * VPR + i1) * DK;
    double s1 = 0.0;
    for (int d = 0; d < DK; ++d) s1 += q_d[d] * (double)kp[d];
    double val = s1; int arg = i1;
    if (v1 - v2 <= 0.01f) {
      const float* kp2 = keys + ((size_t)row * VPR + i2) * DK;
      double s2 = 0.0;
      for (int d = 0; d < DK; ++d) s2 += q_d[d] * (double)kp2[d];
      if (s2 > val || (s2 == val && i2 < arg)) { val = s2; arg = i2; }
    }
    cval[tid] = val; carg[tid] = arg;
  }
  __syncthreads();

  // exact top-32 among candidates (value desc, row asc)
  if (tid < C) {
    double v = cval[tid]; int row = slotRow[tid]; int rank = 0;
    for (int j = 0; j < C; ++j) {
      double u = cval[j]; int rj = slotRow[j];
      rank += (u > v) | ((u == v) & (rj < row));
    }
    if (rank < KTOP) { fgid[rank] = row * VPR + carg[tid]; fval[rank] = v; }
  }
  __syncthreads();

  // masked softmax over the 32 selected (f64), write weights + entity ids
  if (tid < KTOP) {
    int gid = fgid[tid];
    double sc = fval[tid] - (1.0 - (double)memmask[gid]) * 1e10;
    double mx = sc;
#pragma unroll
    for (int off = 16; off >= 1; off >>= 1) mx = fmax(mx, __shfl_xor(mx, off, 32));
    double e = exp(sc - mx), ss = e;
#pragma unroll
    for (int off = 16; off >= 1; off >>= 1) ss += __shfl_xor(ss, off, 32);
    float w = (float)(e / ss);
    out_w[(size_t)m * KTOP + tid] = w;
    out_ids[(size_t)m * KTOP + tid] = (float)eids[gid];
    wsm[tid] = w;
  }
  __syncthreads();

  // pooled = attn @ top_values
  for (int d = tid; d < DV; d += 256) {
    float acc = 0.f;
#pragma unroll 8
    for (int i = 0; i < KTOP; ++i) acc += wsm[i] * mvals[(size_t)fgid[i] * DV + d];
    pooled[(size_t)m * DV + d] = acc;
  }
}

// ---------------------------------------------------------------------------
// Kernel 4: projected = pooled @ update_w + b, * mention_mask, scatter-add.
// 4 mentions per block to amortize update_w traffic.
// ---------------------------------------------------------------------------
__global__ __launch_bounds__(256) void k_project(
    const float* __restrict__ pooled, const float* __restrict__ uw,
    const float* __restrict__ ub, const float* __restrict__ mmsk,
    const int* __restrict__ mbp, const int* __restrict__ msp,
    float* __restrict__ delta) {
  int mt = blockIdx.x, tid = threadIdx.x;
  __shared__ float p_s[4 * DV];
  for (int i = tid; i < 4 * DV; i += 256) p_s[i] = pooled[(size_t)mt * 4 * DV + i];
  __syncthreads();
  float a0[4] = {}, a1[4] = {}, a2[4] = {};
  for (int d = 0; d < DV; ++d) {
    float w0 = uw[(size_t)d * H_ + tid];
    float w1 = uw[(size_t)d * H_ + tid + 256];
    float w2 = uw[(size_t)d * H_ + tid + 512];
#pragma unroll
    for (int q = 0; q < 4; ++q) {
      float p = p_s[q * DV + d];
      a0[q] += p * w0; a1[q] += p * w1; a2[q] += p * w2;
    }
  }
#pragma unroll
  for (int q = 0; q < 4; ++q) {
    int m = mt * 4 + q;
    float msk = mmsk[m];
    float* dst = delta + ((size_t)(mbp[m] * T_ + msp[m])) * H_;
    atomicAdd(dst + tid,       (a0[q] + ub[tid])       * msk);
    atomicAdd(dst + tid + 256, (a1[q] + ub[tid + 256]) * msk);
    atomicAdd(dst + tid + 512, (a2[q] + ub[tid + 512]) * msk);
  }
}

// ---------------------------------------------------------------------------
// Kernel 5: LayerNorm over H for every (b,t), reading enc + delta.
// ---------------------------------------------------------------------------
__device__ __forceinline__ float blockReduceSum(float v, float* red, int tid) {
#pragma unroll
  for (int off = 32; off >= 1; off >>= 1) v += __shfl_xor(v, off, 64);
  __syncthreads();                 // protect red[] from previous use
  if ((tid & 63) == 0) red[tid >> 6] = v;
  __syncthreads();
  return red[0] + red[1] + red[2] + red[3];
}

__global__ __launch_bounds__(256) void k_ln(
    const float* __restrict__ enc, const float* __restrict__ delta,
    const float* __restrict__ lns, const float* __restrict__ lnb,
    float* __restrict__ out) {
  int r = blockIdx.x, tid = threadIdx.x;
  size_t base = (size_t)r * H_;
  __shared__ float red[4];
  float x0 = enc[base + tid]       + delta[base + tid];
  float x1 = enc[base + tid + 256] + delta[base + tid + 256];
  float x2 = enc[base + tid + 512] + delta[base + tid + 512];
  float mu = blockReduceSum(x0 + x1 + x2, red, tid) * (1.f / 768.f);
  float d0 = x0 - mu, d1 = x1 - mu, d2 = x2 - mu;
  float var = blockReduceSum(d0 * d0 + d1 * d1 + d2 * d2, red, tid) * (1.f / 768.f);
  float rs = 1.f / sqrtf(var + 1e-12f);
  out[base + tid]       = d0 * rs * lns[tid]       + lnb[tid];
  out[base + tid + 256] = d1 * rs * lns[tid + 256] + lnb[tid + 256];
  out[base + tid + 512] = d2 * rs * lns[tid + 512] + lnb[tid + 512];
}

// ---------------------------------------------------------------------------
extern "C" void kernel_launch(void* const* d_in, const int* in_sizes, int n_in,
                              void* d_out, int out_size, void* d_ws, size_t ws_size,
                              hipStream_t stream) {
  (void)in_sizes; (void)n_in; (void)out_size; (void)ws_size;
  const float* enc     = (const float*)d_in[0];
  const int*   mbp     = (const int*)d_in[1];
  const int*   msp     = (const int*)d_in[2];
  const int*   mep     = (const int*)d_in[3];
  const float* mmsk    = (const float*)d_in[4];
  const float* keys    = (const float*)d_in[5];
  const float* mvals   = (const float*)d_in[6];
  const int*   memmask = (const int*)d_in[7];
  const int*   eids    = (const int*)d_in[8];
  const float* qw      = (const float*)d_in[9];
  const float* qb      = (const float*)d_in[10];
  const float* uw      = (const float*)d_in[11];
  const float* ub      = (const float*)d_in[12];
  const float* lns     = (const float*)d_in[13];
  const float* lnb     = (const float*)d_in[14];

  char* ws = (char*)d_ws;
  double* qf64  = (double*)(ws + WS_QF64);
  float*  qf32  = (float*)(ws + WS_QF32);
  float*  rmax1 = (float*)(ws + WS_RMAX1);
  float*  rmax2 = (float*)(ws + WS_RMAX2);
  int*    rarg1 = (int*)(ws + WS_RARG1);
  int*    rarg2 = (int*)(ws + WS_RARG2);
  float*  pooled = (float*)(ws + WS_POOLED);
  float*  delta  = (float*)(ws + WS_DELTA);

  float* out_enc = (float*)d_out;
  float* out_w   = out_enc + (size_t)B_ * T_ * H_;
  float* out_ids = out_w + (size_t)N_ * KTOP;

  hipMemsetAsync(delta, 0, (size_t)B_ * T_ * H_ * 4, stream);
  k_queries<<<N_, 128, 0, stream>>>(enc, mbp, msp, mep, qw, qb, qf64, qf32);
  dim3 gs(NROWS, N_ / TM);
  k_score<<<gs, 256, 0, stream>>>(qf32, keys, rmax1, rmax2, rarg1, rarg2);
  k_select<<<N_, 256, 0, stream>>>(qf64, keys, rmax1, rmax2, rarg1, rarg2,
                                   memmask, eids, mvals, out_w, out_ids, pooled);
  k_project<<<N_ / 4, 256, 0, stream>>>(pooled, uw, ub, mmsk, mbp, msp, delta);
  k_ln<<<B_ * T_, 256, 0, stream>>>(enc, delta, lns, lnb, out_enc);
}

// Round 2
// 428.952 us; speedup vs baseline: 4.3398x; 4.3398x over previous
//
#include <hip/hip_runtime.h>
#include <math.h>

#define B_ 32
#define T_ 128
#define H_ 768
#define N_ 1024
#define M_ 131072
#define DK 128
#define DV 512
#define NROWS 512
#define VPR 256
#define KTOP 32
#define QT 8   // mention tiles of 128 for k_score

typedef __attribute__((ext_vector_type(8))) short short8v;
typedef __attribute__((ext_vector_type(4))) float f32x4;

// ---- workspace layout (bytes) ----
#define WS_QF64   ((size_t)0)
#define WS_QHI    (WS_QF64 + (size_t)N_*DK*8)
#define WS_QLO    (WS_QHI + (size_t)N_*DK*2)
#define WS_RMAX1  (WS_QLO + (size_t)N_*DK*2)
#define WS_RMAX2  (WS_RMAX1 + (size_t)N_*NROWS*4)
#define WS_RARG1  (WS_RMAX2 + (size_t)N_*NROWS*4)
#define WS_RARG2  (WS_RARG1 + (size_t)N_*NROWS*4)
#define WS_POOLED (WS_RARG2 + (size_t)N_*NROWS*4)
#define WS_DELTA  (WS_POOLED + (size_t)N_*DV*4)
#define WS_KHI    (WS_DELTA + (size_t)B_*T_*H_*4)
#define WS_KLO    (WS_KHI + (size_t)M_*DK*2)
// total ~88 MB

__device__ __forceinline__ unsigned short bf16_rn(float x) {
  unsigned u = __float_as_uint(x);
  unsigned r = u + 0x7FFFu + ((u >> 16) & 1u);
  return (unsigned short)(r >> 16);
}

// ---------------------------------------------------------------------------
// Kernel 0: split keys into hi/lo bf16, stored in the swizzled LDS-linear
// image: short index = row*32768 + kir*128 + (gt ^ (kir&15))*8 + (d&7)
// ---------------------------------------------------------------------------
__global__ __launch_bounds__(256) void k_split(
    const float* __restrict__ keys, unsigned short* __restrict__ khi,
    unsigned short* __restrict__ klo) {
  int t = threadIdx.x;
  int key = blockIdx.x * 16 + (t >> 4);
  int gt = t & 15;  // dim granule (8 dims)
  const float* src = keys + (size_t)key * DK + gt * 8;
  float4 f0 = *(const float4*)(src);
  float4 f1 = *(const float4*)(src + 4);
  float f[8] = {f0.x, f0.y, f0.z, f0.w, f1.x, f1.y, f1.z, f1.w};
  unsigned h[8], l[8];
#pragma unroll
  for (int i = 0; i < 8; ++i) {
    h[i] = bf16_rn(f[i]);
    float fh = __uint_as_float(h[i] << 16);
    l[i] = bf16_rn(f[i] - fh);
  }
  int kir = key & 255, row = key >> 8;
  int g = gt ^ (kir & 15);
  size_t base = (size_t)row * 32768 + (size_t)kir * 128 + g * 8;
  uint4 uh = {h[0] | (h[1] << 16), h[2] | (h[3] << 16),
              h[4] | (h[5] << 16), h[6] | (h[7] << 16)};
  uint4 ul = {l[0] | (l[1] << 16), l[2] | (l[3] << 16),
              l[4] | (l[5] << 16), l[6] | (l[7] << 16)};
  *(uint4*)(khi + base) = uh;
  *(uint4*)(klo + base) = ul;
}

// ---------------------------------------------------------------------------
// Kernel 1: queries (f64 acc) -> qf64 + fragment-ordered bf16 hi/lo packs
// ---------------------------------------------------------------------------
__global__ __launch_bounds__(128) void k_queries(
    const float* __restrict__ enc, const int* __restrict__ mbp,
    const int* __restrict__ msp, const int* __restrict__ mep,
    const float* __restrict__ qw, const float* __restrict__ qb,
    double* __restrict__ qf64, unsigned short* __restrict__ qhi,
    unsigned short* __restrict__ qlo) {
  int m = blockIdx.x, d = threadIdx.x;
  __shared__ float se[H_], ee[H_];
  int b = mbp[m], s = msp[m], e = mep[m];
  const float* rs = enc + ((size_t)(b * T_ + s)) * H_;
  const float* re = enc + ((size_t)(b * T_ + e)) * H_;
  for (int h = d; h < H_; h += 128) { se[h] = rs[h]; ee[h] = re[h]; }
  __syncthreads();
  double acc = (double)qb[d];
  for (int h = 0; h < H_; ++h) acc += (double)se[h] * (double)qw[(size_t)h * DK + d];
  for (int h = 0; h < H_; ++h) acc += (double)ee[h] * (double)qw[(size_t)(H_ + h) * DK + d];
  qf64[(size_t)m * DK + d] = acc;
  float qf = (float)acc;
  unsigned hv = bf16_rn(qf);
  float fh = __uint_as_float(hv << 16);
  unsigned lv = bf16_rn(qf - fh);
  int mtg = m >> 4, r16 = m & 15, ks = d >> 5, sub = (d >> 3) & 3;
  size_t idx = ((size_t)(mtg * 4 + ks) * 64 + sub * 16 + r16) * 8 + (d & 7);
  qhi[idx] = (unsigned short)hv;
  qlo[idx] = (unsigned short)lv;
}

// ---------------------------------------------------------------------------
// Kernel 2: MFMA split-bf16 scoring + per-row top-2 (index packed in low
// 8 mantissa bits). Block: 512 thr = 8 waves (2 mg x 4 kg); tile 128m x 256k.
// ---------------------------------------------------------------------------
__global__ __launch_bounds__(512, 2) void k_score(
    const unsigned short* __restrict__ khi, const unsigned short* __restrict__ klo,
    const unsigned short* __restrict__ qhi, const unsigned short* __restrict__ qlo,
    float* __restrict__ rmax1, float* __restrict__ rmax2,
    int* __restrict__ rarg1, int* __restrict__ rarg2) {
  __shared__ unsigned short klds[2][VPR * DK];  // 128 KB, swizzled image
  __shared__ float mbuf[128][8];
  int Q = blockIdx.x, row = blockIdx.y;
  int tid = threadIdx.x;
  int lane = tid & 63, wave = tid >> 6;
  int mg = wave >> 2, kg = wave & 3;
  int l15 = lane & 15, l4 = lane >> 4;

  // stage the row's 256 keys hi/lo (pre-swizzled in global -> linear copy)
  const unsigned short* srcH = khi + (size_t)row * 32768;
  const unsigned short* srcL = klo + (size_t)row * 32768;
#pragma unroll
  for (int j = 0; j < 8; ++j) {
    int G = tid + 512 * j;  // granule 0..4095
    *(uint4*)(&klds[0][G * 8]) = *(const uint4*)(srcH + G * 8);
    *(uint4*)(&klds[1][G * 8]) = *(const uint4*)(srcL + G * 8);
  }
  __syncthreads();

  f32x4 acc[4][4];
#pragma unroll
  for (int a = 0; a < 4; ++a)
#pragma unroll
    for (int b = 0; b < 4; ++b) acc[a][b] = (f32x4){0.f, 0.f, 0.f, 0.f};

#pragma unroll
  for (int ks = 0; ks < 4; ++ks) {
    short8v bh[4], bl[4];
#pragma unroll
    for (int kt = 0; kt < 4; ++kt) {
      int kir = kg * 64 + kt * 16 + l15;
      int g = (l4 + 4 * ks) ^ l15;
      int off = kir * 128 + g * 8;
      bh[kt] = *(const short8v*)(&klds[0][off]);
      bl[kt] = *(const short8v*)(&klds[1][off]);
    }
#pragma unroll
    for (int mt = 0; mt < 4; ++mt) {
      int mtg = Q * 8 + mg * 4 + mt;
      size_t aoff = ((size_t)(mtg * 4 + ks) * 64 + lane) * 8;
      short8v ah = *(const short8v*)(qhi + aoff);
      short8v al = *(const short8v*)(qlo + aoff);
#pragma unroll
      for (int kt = 0; kt < 4; ++kt) {
        acc[mt][kt] = __builtin_amdgcn_mfma_f32_16x16x32_bf16(ah, bh[kt], acc[mt][kt], 0, 0, 0);
        acc[mt][kt] = __builtin_amdgcn_mfma_f32_16x16x32_bf16(ah, bl[kt], acc[mt][kt], 0, 0, 0);
        acc[mt][kt] = __builtin_amdgcn_mfma_f32_16x16x32_bf16(al, bh[kt], acc[mt][kt], 0, 0, 0);
      }
    }
  }

  // top-2 per mention over this wave's 64 keys (index in low 8 bits)
#pragma unroll
  for (int mt = 0; mt < 4; ++mt) {
#pragma unroll
    for (int r = 0; r < 4; ++r) {
      float p[4];
#pragma unroll
      for (int kt = 0; kt < 4; ++kt) {
        unsigned bits = __float_as_uint(acc[mt][kt][r]);
        unsigned idx = (unsigned)(kg * 64 + kt * 16 + l15);
        p[kt] = __uint_as_float((bits & 0xFFFFFF00u) | idx);
      }
      float m1 = fmaxf(p[0], p[1]), n1 = fminf(p[0], p[1]);
      float m2 = fmaxf(p[2], p[3]), n2 = fminf(p[2], p[3]);
      float v1 = fmaxf(m1, m2);
      float v2 = fmaxf(fminf(m1, m2), fmaxf(n1, n2));
#pragma unroll
      for (int s = 1; s < 16; s <<= 1) {
        float w1 = __shfl_xor(v1, s, 16);
        float w2 = __shfl_xor(v2, s, 16);
        float a = fmaxf(v1, w1);
        v2 = fmaxf(fminf(v1, w1), fmaxf(v2, w2));
        v1 = a;
      }
      if (l15 == 0) {
        int mloc = mg * 64 + mt * 16 + l4 * 4 + r;
        mbuf[mloc][kg * 2] = v1;
        mbuf[mloc][kg * 2 + 1] = v2;
      }
    }
  }
  __syncthreads();

  if (tid < 128) {
    float v1 = -INFINITY, v2 = -INFINITY;
#pragma unroll
    for (int j = 0; j < 8; ++j) {
      float v = mbuf[tid][j];
      float t1 = fmaxf(v1, v);
      v2 = fmaxf(v2, fminf(v1, v));
      v1 = t1;
    }
    size_t o = ((size_t)(Q * 128 + tid)) * NROWS + row;
    rmax1[o] = v1;
    rmax2[o] = v2;
    rarg1[o] = (int)(__float_as_uint(v1) & 0xFFu);
    rarg2[o] = (int)(__float_as_uint(v2) & 0xFFu);
  }
}

// ---------------------------------------------------------------------------
// Kernel 3: per-mention exact selection (f64 rescoring), softmax, pooling.
// ---------------------------------------------------------------------------
__global__ __launch_bounds__(256) void k_select(
    const double* __restrict__ qf64, const float* __restrict__ keys,
    const float* __restrict__ rmax1, const float* __restrict__ rmax2,
    const int* __restrict__ rarg1, const int* __restrict__ rarg2,
    const int* __restrict__ memmask, const int* __restrict__ eids,
    const float* __restrict__ mvals,
    float* __restrict__ out_w, float* __restrict__ out_ids,
    float* __restrict__ pooled) {
  int m = blockIdx.x, tid = threadIdx.x;
  __shared__ double q_d[DK];
  __shared__ float  vals[NROWS];
  __shared__ int    slotRow[64];
  __shared__ float  slotV[64];
  __shared__ double cval[64];
  __shared__ int    carg[64];
  __shared__ float  Tsh;
  __shared__ int    Csh;
  __shared__ int    fgid[KTOP];
  __shared__ double fval[KTOP];
  __shared__ float  wsm[KTOP];

  for (int i = tid; i < DK; i += 256) q_d[i] = qf64[(size_t)m * DK + i];
  for (int i = tid; i < NROWS; i += 256) vals[i] = rmax1[(size_t)m * NROWS + i];
  __syncthreads();

  for (int i = tid; i < NROWS; i += 256) {
    float v = vals[i]; int rank = 0;
    for (int j = 0; j < NROWS; ++j) {
      float u = vals[j];
      rank += (u > v) | ((u == v) & (j < i));
    }
    if (rank < 64) { slotRow[rank] = i; slotV[rank] = v; }
    if (rank == KTOP - 1) Tsh = v - 0.01f;
  }
  __syncthreads();
  if (tid == 0) {
    int C = KTOP;
    while (C < 64 && slotV[C] >= Tsh) ++C;
    Csh = C;
  }
  __syncthreads();
  int C = Csh;

  if (tid < C) {
    int row = slotRow[tid];
    size_t o = (size_t)m * NROWS + row;
    float v1 = vals[row], v2 = rmax2[o];
    int i1 = rarg1[o], i2 = rarg2[o];
    const float* kp = keys + ((size_t)row * VPR + i1) * DK;
    double s1 = 0.0;
    for (int d = 0; d < DK; ++d) s1 += q_d[d] * (double)kp[d];
    double val = s1; int arg = i1;
    if (v1 - v2 <= 0.01f) {
      const float* kp2 = keys + ((size_t)row * VPR + i2) * DK;
      double s2 = 0.0;
      for (int d = 0; d < DK; ++d) s2 += q_d[d] * (double)kp2[d];
      if (s2 > val || (s2 == val && i2 < arg)) { val = s2; arg = i2; }
    }
    cval[tid] = val; carg[tid] = arg;
  }
  __syncthreads();

  if (tid < C) {
    double v = cval[tid]; int row = slotRow[tid]; int rank = 0;
    for (int j = 0; j < C; ++j) {
      double u = cval[j]; int rj = slotRow[j];
      rank += (u > v) | ((u == v) & (rj < row));
    }
    if (rank < KTOP) { fgid[rank] = row * VPR + carg[tid]; fval[rank] = v; }
  }
  __syncthreads();

  if (tid < KTOP) {
    int gid = fgid[tid];
    double sc = fval[tid] - (1.0 - (double)memmask[gid]) * 1e10;
    double mx = sc;
#pragma unroll
    for (int off = 16; off >= 1; off >>= 1) mx = fmax(mx, __shfl_xor(mx, off, 32));
    double e = exp(sc - mx), ss = e;
#pragma unroll
    for (int off = 16; off >= 1; off >>= 1) ss += __shfl_xor(ss, off, 32);
    float w = (float)(e / ss);
    out_w[(size_t)m * KTOP + tid] = w;
    out_ids[(size_t)m * KTOP + tid] = (float)eids[gid];
    wsm[tid] = w;
  }
  __syncthreads();

  for (int d = tid; d < DV; d += 256) {
    float acc = 0.f;
#pragma unroll 8
    for (int i = 0; i < KTOP; ++i) acc += wsm[i] * mvals[(size_t)fgid[i] * DV + d];
    pooled[(size_t)m * DV + d] = acc;
  }
}

// ---------------------------------------------------------------------------
// Kernel 4: projected = pooled @ update_w + b, * mention_mask, scatter-add.
// ---------------------------------------------------------------------------
__global__ __launch_bounds__(256) void k_project(
    const float* __restrict__ pooled, const float* __restrict__ uw,
    const float* __restrict__ ub, const float* __restrict__ mmsk,
    const int* __restrict__ mbp, const int* __restrict__ msp,
    float* __restrict__ delta) {
  int mt = blockIdx.x, tid = threadIdx.x;
  __shared__ float p_s[4 * DV];
  for (int i = tid; i < 4 * DV; i += 256) p_s[i] = pooled[(size_t)mt * 4 * DV + i];
  __syncthreads();
  float a0[4] = {}, a1[4] = {}, a2[4] = {};
  for (int d = 0; d < DV; ++d) {
    float w0 = uw[(size_t)d * H_ + tid];
    float w1 = uw[(size_t)d * H_ + tid + 256];
    float w2 = uw[(size_t)d * H_ + tid + 512];
#pragma unroll
    for (int q = 0; q < 4; ++q) {
      float p = p_s[q * DV + d];
      a0[q] += p * w0; a1[q] += p * w1; a2[q] += p * w2;
    }
  }
#pragma unroll
  for (int q = 0; q < 4; ++q) {
    int m = mt * 4 + q;
    float msk = mmsk[m];
    float* dst = delta + ((size_t)(mbp[m] * T_ + msp[m])) * H_;
    atomicAdd(dst + tid,       (a0[q] + ub[tid])       * msk);
    atomicAdd(dst + tid + 256, (a1[q] + ub[tid + 256]) * msk);
    atomicAdd(dst + tid + 512, (a2[q] + ub[tid + 512]) * msk);
  }
}

// ---------------------------------------------------------------------------
// Kernel 5: LayerNorm over H for every (b,t), reading enc + delta.
// ---------------------------------------------------------------------------
__device__ __forceinline__ float blockReduceSum(float v, float* red, int tid) {
#pragma unroll
  for (int off = 32; off >= 1; off >>= 1) v += __shfl_xor(v, off, 64);
  __syncthreads();
  if ((tid & 63) == 0) red[tid >> 6] = v;
  __syncthreads();
  return red[0] + red[1] + red[2] + red[3];
}

__global__ __launch_bounds__(256) void k_ln(
    const float* __restrict__ enc, const float* __restrict__ delta,
    const float* __restrict__ lns, const float* __restrict__ lnb,
    float* __restrict__ out) {
  int r = blockIdx.x, tid = threadIdx.x;
  size_t base = (size_t)r * H_;
  __shared__ float red[4];
  float x0 = enc[base + tid]       + delta[base + tid];
  float x1 = enc[base + tid + 256] + delta[base + tid + 256];
  float x2 = enc[base + tid + 512] + delta[base + tid + 512];
  float mu = blockReduceSum(x0 + x1 + x2, red, tid) * (1.f / 768.f);
  float d0 = x0 - mu, d1 = x1 - mu, d2 = x2 - mu;
  float var = blockReduceSum(d0 * d0 + d1 * d1 + d2 * d2, red, tid) * (1.f / 768.f);
  float rs = 1.f / sqrtf(var + 1e-12f);
  out[base + tid]       = d0 * rs * lns[tid]       + lnb[tid];
  out[base + tid + 256] = d1 * rs * lns[tid + 256] + lnb[tid + 256];
  out[base + tid + 512] = d2 * rs * lns[tid + 512] + lnb[tid + 512];
}

// ---------------------------------------------------------------------------
extern "C" void kernel_launch(void* const* d_in, const int* in_sizes, int n_in,
                              void* d_out, int out_size, void* d_ws, size_t ws_size,
                              hipStream_t stream) {
  (void)in_sizes; (void)n_in; (void)out_size; (void)ws_size;
  const float* enc     = (const float*)d_in[0];
  const int*   mbp     = (const int*)d_in[1];
  const int*   msp     = (const int*)d_in[2];
  const int*   mep     = (const int*)d_in[3];
  const float* mmsk    = (const float*)d_in[4];
  const float* keys    = (const float*)d_in[5];
  const float* mvals   = (const float*)d_in[6];
  const int*   memmask = (const int*)d_in[7];
  const int*   eids    = (const int*)d_in[8];
  const float* qw      = (const float*)d_in[9];
  const float* qb      = (const float*)d_in[10];
  const float* uw      = (const float*)d_in[11];
  const float* ub      = (const float*)d_in[12];
  const float* lns     = (const float*)d_in[13];
  const float* lnb     = (const float*)d_in[14];

  char* ws = (char*)d_ws;
  double*         qf64   = (double*)(ws + WS_QF64);
  unsigned short* qhi    = (unsigned short*)(ws + WS_QHI);
  unsigned short* qlo    = (unsigned short*)(ws + WS_QLO);
  float*          rmax1  = (float*)(ws + WS_RMAX1);
  float*          rmax2  = (float*)(ws + WS_RMAX2);
  int*            rarg1  = (int*)(ws + WS_RARG1);
  int*            rarg2  = (int*)(ws + WS_RARG2);
  float*          pooled = (float*)(ws + WS_POOLED);
  float*          delta  = (float*)(ws + WS_DELTA);
  unsigned short* khi    = (unsigned short*)(ws + WS_KHI);
  unsigned short* klo    = (unsigned short*)(ws + WS_KLO);

  float* out_enc = (float*)d_out;
  float* out_w   = out_enc + (size_t)B_ * T_ * H_;
  float* out_ids = out_w + (size_t)N_ * KTOP;

  hipMemsetAsync(delta, 0, (size_t)B_ * T_ * H_ * 4, stream);
  k_split<<<M_ / 16, 256, 0, stream>>>(keys, khi, klo);
  k_queries<<<N_, 128, 0, stream>>>(enc, mbp, msp, mep, qw, qb, qf64, qhi, qlo);
  dim3 gs(QT, NROWS);
  k_score<<<gs, 512, 0, stream>>>(khi, klo, qhi, qlo, rmax1, rmax2, rarg1, rarg2);
  k_select<<<N_, 256, 0, stream>>>(qf64, keys, rmax1, rmax2, rarg1, rarg2,
                                   memmask, eids, mvals, out_w, out_ids, pooled);
  k_project<<<N_ / 4, 256, 0, stream>>>(pooled, uw, ub, mmsk, mbp, msp, delta);
  k_ln<<<B_ * T_, 256, 0, stream>>>(enc, delta, lns, lnb, out_enc);
}